// Round 2
// baseline (89.498 us; speedup 1.0000x reference)
//
#include <hip/hip_runtime.h>

#define N_WIRES 4
#define N_LAYERS 3
#define DIM 16

// ---------------------------------------------------------------------------
// Setup kernel: compute the 12 batch-independent Rot matrices into d_ws.
// Layout per gate g: W[g*8 + {re00,im00,re01,im01,re10,im10,re11,im11}]
// ---------------------------------------------------------------------------
__global__ void qenc_setup(const float* __restrict__ params, float* __restrict__ W) {
    const int t = threadIdx.x;
    if (t < N_LAYERS * N_WIRES) {
        const float phi = params[t * 3 + 0];
        const float th  = params[t * 3 + 1];
        const float om  = params[t * 3 + 2];
        float c, s, ca, sa, cb, sb;
        __sincosf(0.5f * th, &s, &c);
        __sincosf(0.5f * (phi + om), &sa, &ca);
        __sincosf(0.5f * (phi - om), &sb, &cb);
        // U = RZ(om) @ RY(th) @ RZ(phi)
        W[t * 8 + 0] =  c * ca;  W[t * 8 + 1] = -c * sa;
        W[t * 8 + 2] = -s * cb;  W[t * 8 + 3] = -s * sb;
        W[t * 8 + 4] =  s * cb;  W[t * 8 + 5] = -s * sb;
        W[t * 8 + 6] =  c * ca;  W[t * 8 + 7] =  c * sa;
    }
}

// ---------------------------------------------------------------------------
// Main kernel
// ---------------------------------------------------------------------------
__device__ __forceinline__ float2 cmul(float2 a, float2 b) {
    return make_float2(a.x * b.x - a.y * b.y, a.x * b.y + a.y * b.x);
}

// One 2x2 complex butterfly on (A,B) with matrix [[u00,u01],[u10,u11]].
// u* come from SGPRs (scalar loads of W) -> each v_fma uses exactly 1 SGPR.
__device__ __forceinline__ void bfly(float2& A, float2& B,
    float u00r, float u00i, float u01r, float u01i,
    float u10r, float u10i, float u11r, float u11i) {
    const float v0r = A.x, v0i = A.y, v1r = B.x, v1i = B.y;
    A.x = u00r * v0r - u00i * v0i + u01r * v1r - u01i * v1i;
    A.y = u00r * v0i + u00i * v0r + u01r * v1i + u01i * v1r;
    B.x = u10r * v0r - u10i * v0i + u11r * v1r - u11i * v1i;
    B.y = u10r * v0i + u10i * v0r + u11r * v1i + u11i * v1r;
}

// Gate g applied to 8 explicit literal-index pairs (guarantees st[] stays in regs)
#define GATE(g, a0,b0,a1,b1,a2,b2,a3,b3,a4,b4,a5,b5,a6,b6,a7,b7)              \
    {                                                                          \
        const float u00r = W[(g)*8+0], u00i = W[(g)*8+1];                      \
        const float u01r = W[(g)*8+2], u01i = W[(g)*8+3];                      \
        const float u10r = W[(g)*8+4], u10i = W[(g)*8+5];                      \
        const float u11r = W[(g)*8+6], u11i = W[(g)*8+7];                      \
        bfly(st[a0], st[b0], u00r,u00i,u01r,u01i,u10r,u10i,u11r,u11i);         \
        bfly(st[a1], st[b1], u00r,u00i,u01r,u01i,u10r,u10i,u11r,u11i);         \
        bfly(st[a2], st[b2], u00r,u00i,u01r,u01i,u10r,u10i,u11r,u11i);         \
        bfly(st[a3], st[b3], u00r,u00i,u01r,u01i,u10r,u10i,u11r,u11i);         \
        bfly(st[a4], st[b4], u00r,u00i,u01r,u01i,u10r,u10i,u11r,u11i);         \
        bfly(st[a5], st[b5], u00r,u00i,u01r,u01i,u10r,u10i,u11r,u11i);         \
        bfly(st[a6], st[b6], u00r,u00i,u01r,u01i,u10r,u10i,u11r,u11i);         \
        bfly(st[a7], st[b7], u00r,u00i,u01r,u01i,u10r,u10i,u11r,u11i);         \
    }

#define SW(a,b) { const float2 t_ = st[a]; st[a] = st[b]; st[b] = t_; }

// qubit masks: q0->8, q1->4, q2->2, q3->1; pairs are (k, k|m) for k with bit m clear
#define LAYER(l)                                                               \
    GATE((l)*4+0, 0,8, 1,9, 2,10, 3,11, 4,12, 5,13, 6,14, 7,15)                \
    GATE((l)*4+1, 0,4, 1,5, 2,6,  3,7,  8,12, 9,13, 10,14, 11,15)              \
    GATE((l)*4+2, 0,2, 1,3, 4,6,  5,7,  8,10, 9,11, 12,14, 13,15)              \
    GATE((l)*4+3, 0,1, 2,3, 4,5,  6,7,  8,9,  10,11, 12,13, 14,15)             \
    /* CNOT(0,1) */ SW(8,12) SW(9,13) SW(10,14) SW(11,15)                      \
    /* CNOT(1,2) */ SW(4,6)  SW(5,7)  SW(12,14) SW(13,15)                      \
    /* CNOT(2,3) */ SW(2,3)  SW(6,7)  SW(10,11) SW(14,15)

__global__ __launch_bounds__(256, 4) void qenc_main(
    const float4* __restrict__ x4, const float* __restrict__ W,
    float4* __restrict__ out4, int B)
{
    const int b = blockIdx.x * blockDim.x + threadIdx.x;
    if (b >= B) return;

    const float4 xv = x4[b];
    const float xa[4] = {xv.x, xv.y, xv.z, xv.w};
    float cx[4], sx[4];
#pragma unroll
    for (int i = 0; i < 4; i++) __sincosf(0.5f * xa[i], &sx[i], &cx[i]);

    // Encoding: wire i gets RY(x[i+3]) RX(x[i+2]) RZ(x[i+1]) RY(x[i]) |0>
    float2 w0[4], w1[4];
#pragma unroll
    for (int i = 0; i < 4; i++) {
        const int i1 = (i + 1) & 3, i2 = (i + 2) & 3, i3 = (i + 3) & 3;
        const float r0 = cx[i], r1 = sx[i];                       // RY|0>
        float2 n0 = make_float2(r0 * cx[i1], -r0 * sx[i1]);       // RZ
        float2 n1 = make_float2(r1 * cx[i1],  r1 * sx[i1]);
        const float c2 = cx[i2], s2 = sx[i2];                     // RX
        float2 m0 = make_float2(c2 * n0.x + s2 * n1.y,  c2 * n0.y - s2 * n1.x);
        float2 m1 = make_float2(s2 * n0.y + c2 * n1.x, -s2 * n0.x + c2 * n1.y);
        const float c3 = cx[i3], s3 = sx[i3];                     // RY
        w0[i] = make_float2(c3 * m0.x - s3 * m1.x, c3 * m0.y - s3 * m1.y);
        w1[i] = make_float2(s3 * m0.x + c3 * m1.x, s3 * m0.y + c3 * m1.y);
    }

    // Tensor product into 16 amplitudes (wire 0 = MSB)
    float2 p01[4], p23[4];
    p01[0] = cmul(w0[0], w0[1]); p01[1] = cmul(w0[0], w1[1]);
    p01[2] = cmul(w1[0], w0[1]); p01[3] = cmul(w1[0], w1[1]);
    p23[0] = cmul(w0[2], w0[3]); p23[1] = cmul(w0[2], w1[3]);
    p23[2] = cmul(w1[2], w0[3]); p23[3] = cmul(w1[2], w1[3]);

    float2 st[16];
    st[ 0] = cmul(p01[0], p23[0]); st[ 1] = cmul(p01[0], p23[1]);
    st[ 2] = cmul(p01[0], p23[2]); st[ 3] = cmul(p01[0], p23[3]);
    st[ 4] = cmul(p01[1], p23[0]); st[ 5] = cmul(p01[1], p23[1]);
    st[ 6] = cmul(p01[1], p23[2]); st[ 7] = cmul(p01[1], p23[3]);
    st[ 8] = cmul(p01[2], p23[0]); st[ 9] = cmul(p01[2], p23[1]);
    st[10] = cmul(p01[2], p23[2]); st[11] = cmul(p01[2], p23[3]);
    st[12] = cmul(p01[3], p23[0]); st[13] = cmul(p01[3], p23[1]);
    st[14] = cmul(p01[3], p23[2]); st[15] = cmul(p01[3], p23[3]);

    LAYER(0)
    LAYER(1)
    LAYER(2)

    // Probabilities
    float q0  = st[ 0].x*st[ 0].x + st[ 0].y*st[ 0].y;
    float q1  = st[ 1].x*st[ 1].x + st[ 1].y*st[ 1].y;
    float q2  = st[ 2].x*st[ 2].x + st[ 2].y*st[ 2].y;
    float q3  = st[ 3].x*st[ 3].x + st[ 3].y*st[ 3].y;
    float q4  = st[ 4].x*st[ 4].x + st[ 4].y*st[ 4].y;
    float q5  = st[ 5].x*st[ 5].x + st[ 5].y*st[ 5].y;
    float q6  = st[ 6].x*st[ 6].x + st[ 6].y*st[ 6].y;
    float q7  = st[ 7].x*st[ 7].x + st[ 7].y*st[ 7].y;
    float q8  = st[ 8].x*st[ 8].x + st[ 8].y*st[ 8].y;
    float q9  = st[ 9].x*st[ 9].x + st[ 9].y*st[ 9].y;
    float q10 = st[10].x*st[10].x + st[10].y*st[10].y;
    float q11 = st[11].x*st[11].x + st[11].y*st[11].y;
    float q12 = st[12].x*st[12].x + st[12].y*st[12].y;
    float q13 = st[13].x*st[13].x + st[13].y*st[13].y;
    float q14 = st[14].x*st[14].x + st[14].y*st[14].y;
    float q15 = st[15].x*st[15].x + st[15].y*st[15].y;

    // Hadamard-tree signed sums
    const float a0 = q0+q1,  a1 = q2+q3,  a2 = q4+q5,   a3 = q6+q7;
    const float a4 = q8+q9,  a5 = q10+q11, a6 = q12+q13, a7 = q14+q15;
    const float e0 = q0-q1,  e1 = q2-q3,  e2 = q4-q5,   e3 = q6-q7;
    const float e4 = q8-q9,  e5 = q10-q11, e6 = q12-q13, e7 = q14-q15;
    const float z3 = ((e0+e1)+(e2+e3)) + ((e4+e5)+(e6+e7));
    const float b0 = a0+a1, b1 = a2+a3, b2 = a4+a5, b3 = a6+a7;
    const float f0 = a0-a1, f1 = a2-a3, f2 = a4-a5, f3 = a6-a7;
    const float z2 = (f0+f1) + (f2+f3);
    const float z1 = (b0-b1) + (b2-b3);
    const float z0 = (b0+b1) - (b2+b3);

    out4[b] = make_float4(z0, z1, z2, z3);
}

extern "C" void kernel_launch(void* const* d_in, const int* in_sizes, int n_in,
                              void* d_out, int out_size, void* d_ws, size_t ws_size,
                              hipStream_t stream) {
    const float* x      = (const float*)d_in[0];
    const float* params = (const float*)d_in[1];
    float* out          = (float*)d_out;
    float* W            = (float*)d_ws;   // 96 floats of gate matrices
    const int B = in_sizes[0] / 4;        // x is (B, 4) float32

    qenc_setup<<<1, 64, 0, stream>>>(params, W);

    const int block = 256;
    const int grid = (B + block - 1) / block;
    qenc_main<<<grid, block, 0, stream>>>((const float4*)x, W, (float4*)out, B);
}